// Round 2
// baseline (9098.237 us; speedup 1.0000x reference)
//
#include <hip/hip_runtime.h>
#include <cstdint>
#include <cstddef>

#define T_SEQ 4096
#define EMB_D 512
#define HDIM 512
#define G4 2048
#define NTAGS 24
#define START_TAG 22
#define STOP_TAG 23
#define NEGV -10000.0f
#define NBLK 32      // persistent blocks per direction
#define HSLICE 16    // hidden units per block
#define SENT 0xFFFFFFFFu   // -NaN bit pattern; |h|<1 can never equal this

// ---------------------------------------------------------------------------
// 1) xg[dir][t][j] = dot(emb[sent[t]], w_ih[j]) + b_ih[j] + b_hh[j]
// ---------------------------------------------------------------------------
__global__ __launch_bounds__(256) void gemm_xg_kernel(
    const int* __restrict__ sent, const float* __restrict__ emb,
    const float* __restrict__ w_ih_f, const float* __restrict__ b_ih_f, const float* __restrict__ b_hh_f,
    const float* __restrict__ w_ih_b, const float* __restrict__ b_ih_b, const float* __restrict__ b_hh_b,
    float* __restrict__ xg)
{
    const int dir = blockIdx.z;
    const float* W  = dir ? w_ih_b : w_ih_f;
    const float* bi = dir ? b_ih_b : b_ih_f;
    const float* bh = dir ? b_hh_b : b_hh_f;
    const int m0 = blockIdx.y * 64;   // t
    const int n0 = blockIdx.x * 64;   // gate row j
    const int tid = threadIdx.x;

    __shared__ __attribute__((aligned(16))) float As[32][64];  // [k][t]
    __shared__ __attribute__((aligned(16))) float Bs[32][64];  // [k][j]

    const int lrow = tid >> 2;          // 0..63
    const int lk   = (tid & 3) * 8;     // 0,8,16,24

    const int srow = sent[m0 + lrow];
    const float* aptr = emb + (size_t)srow * EMB_D + lk;
    const float* bptr = W   + (size_t)(n0 + lrow) * EMB_D + lk;

    const int ty = tid >> 4;   // 0..15 (M)
    const int tx = tid & 15;   // 0..15 (N)

    float acc[4][4];
    #pragma unroll
    for (int i = 0; i < 4; ++i)
        #pragma unroll
        for (int j = 0; j < 4; ++j) acc[i][j] = 0.f;

    for (int kk = 0; kk < EMB_D; kk += 32) {
        float4 a0 = *(const float4*)(aptr + kk);
        float4 a1 = *(const float4*)(aptr + kk + 4);
        float4 b0 = *(const float4*)(bptr + kk);
        float4 b1 = *(const float4*)(bptr + kk + 4);
        __syncthreads();   // previous iteration's compute done before overwrite
        As[lk+0][lrow]=a0.x; As[lk+1][lrow]=a0.y; As[lk+2][lrow]=a0.z; As[lk+3][lrow]=a0.w;
        As[lk+4][lrow]=a1.x; As[lk+5][lrow]=a1.y; As[lk+6][lrow]=a1.z; As[lk+7][lrow]=a1.w;
        Bs[lk+0][lrow]=b0.x; Bs[lk+1][lrow]=b0.y; Bs[lk+2][lrow]=b0.z; Bs[lk+3][lrow]=b0.w;
        Bs[lk+4][lrow]=b1.x; Bs[lk+5][lrow]=b1.y; Bs[lk+6][lrow]=b1.z; Bs[lk+7][lrow]=b1.w;
        __syncthreads();
        #pragma unroll
        for (int k = 0; k < 32; ++k) {
            float4 av = *(const float4*)&As[k][ty*4];
            float4 bv = *(const float4*)&Bs[k][tx*4];
            acc[0][0]+=av.x*bv.x; acc[0][1]+=av.x*bv.y; acc[0][2]+=av.x*bv.z; acc[0][3]+=av.x*bv.w;
            acc[1][0]+=av.y*bv.x; acc[1][1]+=av.y*bv.y; acc[1][2]+=av.y*bv.z; acc[1][3]+=av.y*bv.w;
            acc[2][0]+=av.z*bv.x; acc[2][1]+=av.z*bv.y; acc[2][2]+=av.z*bv.z; acc[2][3]+=av.z*bv.w;
            acc[3][0]+=av.w*bv.x; acc[3][1]+=av.w*bv.y; acc[3][2]+=av.w*bv.z; acc[3][3]+=av.w*bv.w;
        }
    }
    #pragma unroll
    for (int i = 0; i < 4; ++i) {
        const int t = m0 + ty*4 + i;
        float* crow = xg + ((size_t)dir*T_SEQ + t) * G4 + n0 + tx*4;
        #pragma unroll
        for (int j = 0; j < 4; ++j) {
            const int jg = n0 + tx*4 + j;
            crow[j] = acc[i][j] + bi[jg] + bh[jg];
        }
    }
}

// ---------------------------------------------------------------------------
// 2) Bidirectional LSTM with XCD co-location (see prior rounds). This round:
//    THE xg PREFETCH IS MOVED TO AFTER THE POLL LOOP.
//    Mechanism: vmcnt is an in-order counter; the poll loop's
//    s_waitcnt vmcnt(0) (needed for the atomic load it just issued) also
//    drains any OLDER outstanding load. With the xg load issued before the
//    poll, every step's poll on wave 0 — the wave whose tail produces the
//    h-store that gates all other blocks — first waited out the full xg
//    L3/HBM latency (~400-900cy). Prefetch *distance* never mattered; the
//    issue point relative to the poll did. Now: poll -> fence -> issue xg
//    for t+1 -> dot. The load completes under dot+B2+tail+next-poll-spin.
//    asm memory fence pins the issue point (the load is speculatable and
//    LLVM would otherwise hoist it back above the poll loop).
// ---------------------------------------------------------------------------
__global__ __attribute__((amdgpu_waves_per_eu(2, 2))) __launch_bounds__(512)
void bilstm_kernel(
    const float* __restrict__ w_hh_f, const float* __restrict__ w_hh_b,
    const float* __restrict__ h0, const float* __restrict__ c0,
    const float* __restrict__ xg,
    uint32_t* __restrict__ h_hist,   // [2][T][HDIM] float bits, pre-set SENT
    int* __restrict__ claim)         // [8] per-XCD rank counters, pre-zeroed
{
    uint32_t xcc;
    asm volatile("s_getreg_b32 %0, hwreg(HW_REG_XCC_ID)" : "=s"(xcc));
    xcc &= 7u;

    __shared__ int rank_s;
    if (threadIdx.x == 0)
        rank_s = __hip_atomic_fetch_add(&claim[xcc], 1, __ATOMIC_RELAXED,
                                        __HIP_MEMORY_SCOPE_AGENT);
    __syncthreads();
    const int rank = rank_s;

    int dir;
    if (xcc == 0) dir = 0;
    else if (xcc == 1) dir = 1;
    else return;
    if (rank >= NBLK) return;
    const int b = rank;

    const int tid = threadIdx.x;    // 512
    const int q   = tid >> 6;       // 0..7 : 64-wide slice of h
    const int rl  = tid & 63;       // 0..63: local gate row
    const int g2  = rl >> 4;        // 0..3 : i,f,g,o
    const int hu  = rl & 15;
    const int row = g2 * HDIM + b * HSLICE + hu;   // global gate row

    const float* Wrow = (dir ? w_hh_b : w_hh_f) + (size_t)row * HDIM + q * 64;
    float w[64];
    #pragma unroll
    for (int j = 0; j < 16; ++j) {
        float4 v = ((const float4*)Wrow)[j];
        w[4*j+0]=v.x; w[4*j+1]=v.y; w[4*j+2]=v.z; w[4*j+3]=v.w;
    }
    // Pin weights in VGPRs (R5: 7.17->6.63ms; budget 256 via waves_per_eu(2,2))
    #pragma unroll
    for (int i = 0; i < 64; ++i) asm volatile("" : "+v"(w[i]));

    __shared__ __attribute__((aligned(16))) float part[2][512];

    float c = (tid < HSLICE) ? c0[dir*HDIM + b*HSLICE + tid] : 0.f;

    const float* xgd = xg + (size_t)dir * T_SEQ * G4;
    uint32_t* hh = h_hist + (size_t)dir * T_SEQ * HDIM;

    // preload xg for idx=0 (consumed this step's tail; complete long before
    // the first poll at idx=1)
    float xv_cur = 0.f;
    if (tid < 64) {
        const int t0 = dir ? (T_SEQ - 1) : 0;
        xv_cur = xgd[(size_t)t0 * G4 + row];
    }

    for (int idx = 0; idx < T_SEQ; ++idx) {
        const int t = dir ? (T_SEQ - 1 - idx) : idx;

        float hv;
        if (idx == 0) {
            hv = h0[dir*HDIM + tid];
        } else {
            const int tprev = dir ? (t + 1) : (t - 1);
            const uint32_t* wp = hh + (size_t)tprev*HDIM + tid;
            uint32_t u;
            do {
                u = __hip_atomic_load(wp, __ATOMIC_RELAXED, __HIP_MEMORY_SCOPE_AGENT);
            } while (u == SENT);
            union { uint32_t uu; float f; } cv; cv.uu = u;
            hv = cv.f;
        }

        // Compile-time fence: the xg load below must be ISSUED here, after the
        // poll's last vmcnt(0), not hoisted above the poll loop. It then has
        // dot+B2+tail+next-poll-spin (~1500cy+) to complete before the next
        // vmcnt(0) touches it.
        asm volatile("" ::: "memory");

        float xv_nxt = 0.f;
        if (tid < 64 && idx + 1 < T_SEQ) {
            const int tn = dir ? (t - 1) : (t + 1);
            xv_nxt = xgd[(size_t)tn * G4 + row];
        }

        // dot: broadcast lane j's polled value via v_readlane (SGPR), FMA with
        // pinned weights. Same values, same expression order -> bit-exact.
        const uint32_t hvu = __float_as_uint(hv);
        float s = 0.f;
        #pragma unroll
        for (int j = 0; j < 16; ++j) {
            const float h0v = __uint_as_float((uint32_t)__builtin_amdgcn_readlane((int)hvu, 4*j+0));
            const float h1v = __uint_as_float((uint32_t)__builtin_amdgcn_readlane((int)hvu, 4*j+1));
            const float h2v = __uint_as_float((uint32_t)__builtin_amdgcn_readlane((int)hvu, 4*j+2));
            const float h3v = __uint_as_float((uint32_t)__builtin_amdgcn_readlane((int)hvu, 4*j+3));
            s += w[4*j+0]*h0v + w[4*j+1]*h1v + w[4*j+2]*h2v + w[4*j+3]*h3v;
        }
        part[idx & 1][tid] = s;
        __syncthreads();                       // B2: partials ready

        if (tid < 64) {                        // wave 0 only
            float g = xv_cur;
            const float* pb = part[idx & 1];
            #pragma unroll
            for (int qq = 0; qq < 8; ++qq) g += pb[qq*64 + tid];
            g = (g2 == 2) ? tanhf(g) : 1.f/(1.f + expf(-g));
            // gates for hidden unit hu live at lanes hu, hu+16, hu+32, hu+48
            float iv = __shfl(g, hu);
            float fg = __shfl(g, hu + 16);
            float gv = __shfl(g, hu + 32);
            float ov = __shfl(g, hu + 48);
            if (tid < HSLICE) {
                c = fg*c + iv*gv;
                union { float f; uint32_t u; } hb; hb.f = ov * tanhf(c);
                __hip_atomic_store(hh + (size_t)t*HDIM + b*HSLICE + tid, hb.u,
                                   __ATOMIC_RELAXED, __HIP_MEMORY_SCOPE_AGENT);
            }
        }
        xv_cur = xv_nxt;
        // part[] rewrite hazard: next write targets part[(idx+1)&1]; the
        // earliest rewrite of part[idx&1] is at idx+2, reachable only after
        // B2(idx+1), which wave0 joins after its reads of part[idx&1] at idx.
    }
}

// ---------------------------------------------------------------------------
// 3) feats[t][tag] = b_tag[tag] + [hf|hb] . w_tag[tag]
// ---------------------------------------------------------------------------
__global__ __launch_bounds__(256) void feats_kernel(
    const float* __restrict__ h_hist, const float* __restrict__ w_tag,
    const float* __restrict__ b_tag, float* __restrict__ feats)
{
    const int t = blockIdx.x;
    const int tid = threadIdx.x;
    __shared__ __attribute__((aligned(16))) float h[1024];
    __shared__ float partl[192];
    for (int i = tid; i < 512; i += 256) {
        h[i]     = h_hist[(size_t)t*HDIM + i];
        h[512+i] = h_hist[(size_t)T_SEQ*HDIM + (size_t)t*HDIM + i];
    }
    __syncthreads();
    if (tid < 192) {
        const int tag = tid >> 3, p = tid & 7;
        const float* wr = w_tag + (size_t)tag*1024 + p*128;
        const float* hp = h + p*128;
        float s = 0.f;
        #pragma unroll 8
        for (int j = 0; j < 128; ++j) s += wr[j]*hp[j];
        partl[tid] = s;
    }
    __syncthreads();
    if (tid < NTAGS) {
        float s = b_tag[tid];
        #pragma unroll
        for (int p = 0; p < 8; ++p) s += partl[tid*8+p];
        feats[(size_t)t*NTAGS + tid] = s;
    }
}

// ---------------------------------------------------------------------------
// 4) Viterbi forward: single wave, LDS broadcast (R2 version — the R5 shfl
//    rewrite regressed 1.6ms; reverted). Strict > keeps FIRST argmax.
// ---------------------------------------------------------------------------
__global__ void viterbi_fwd_kernel(
    const float* __restrict__ feats, const float* __restrict__ trans,
    float* __restrict__ d_out, unsigned char* __restrict__ bp,
    int* __restrict__ best_tag)
{
    const int lane = threadIdx.x;       // 64 threads = 1 wave
    const bool act = lane < NTAGS;
    float tr[NTAGS];
    #pragma unroll
    for (int p = 0; p < NTAGS; ++p)
        tr[p] = act ? trans[lane*NTAGS + p] : NEGV;

    float fv = (lane == START_TAG) ? 0.f : NEGV;
    __shared__ float fvs[NTAGS];
    __shared__ float term[NTAGS];

    float ftn = act ? feats[lane] : 0.f;   // prefetch t=0
    for (int t = 0; t < T_SEQ; ++t) {
        if (act) fvs[lane] = fv;
        __syncthreads();
        float ft = ftn;
        if (act && t + 1 < T_SEQ) ftn = feats[(size_t)(t+1)*NTAGS + lane];
        float bestv = -3.4e38f;
        int argp = 0;
        #pragma unroll
        for (int p = 0; p < NTAGS; ++p) {
            float sc = tr[p] + fvs[p];
            if (sc > bestv) { bestv = sc; argp = p; }
        }
        __syncthreads();   // reads done before next iteration's write
        fv = bestv + ft;
        if (act) bp[(size_t)t*NTAGS + lane] = (unsigned char)argp;
    }
    if (act) { fv += trans[STOP_TAG*NTAGS + lane]; term[lane] = fv; }
    __syncthreads();
    if (lane == 0) {
        float bv = term[0]; int bi = 0;
        #pragma unroll
        for (int p = 1; p < NTAGS; ++p) if (term[p] > bv) { bv = term[p]; bi = p; }
        d_out[0] = bv;
        *best_tag = bi;
    }
}

// ---------------------------------------------------------------------------
// 5) Hierarchical backtrack
// ---------------------------------------------------------------------------
__global__ void bt_compose_kernel(const unsigned char* __restrict__ bp,
                                  unsigned char* __restrict__ segmap)
{
    const int s = blockIdx.x;
    const int tid = threadIdx.x;   // 64
    __shared__ __attribute__((aligned(16))) unsigned char lbp[64*NTAGS];
    const uint32_t* src = (const uint32_t*)(bp + (size_t)s * 64 * NTAGS);
    uint32_t* dst = (uint32_t*)lbp;
    #pragma unroll
    for (int i = 0; i < 6; ++i) dst[tid + 64*i] = src[tid + 64*i];
    __syncthreads();
    if (tid < NTAGS) {
        int m = tid;
        for (int tt = 63; tt >= 0; --tt) m = lbp[tt*NTAGS + m];
        segmap[s*NTAGS + tid] = (unsigned char)m;
    }
}

__global__ void bt_final_kernel(const unsigned char* __restrict__ segmap,
                                const int* __restrict__ best_tag,
                                int* __restrict__ end_tags)
{
    if (threadIdx.x == 0) {
        int tag = *best_tag;
        end_tags[63] = tag;
        for (int s = 63; s >= 1; --s) {
            tag = segmap[s*NTAGS + tag];
            end_tags[s-1] = tag;
        }
    }
}

__global__ void bt_write_kernel(const unsigned char* __restrict__ bp,
                                const int* __restrict__ end_tags,
                                float* __restrict__ out_path)
{
    const int s = blockIdx.x;
    const int tid = threadIdx.x;   // 64
    __shared__ __attribute__((aligned(16))) unsigned char lbp[64*NTAGS];
    const uint32_t* src = (const uint32_t*)(bp + (size_t)s * 64 * NTAGS);
    uint32_t* dst = (uint32_t*)lbp;
    #pragma unroll
    for (int i = 0; i < 6; ++i) dst[tid + 64*i] = src[tid + 64*i];
    __syncthreads();
    if (tid == 0) {
        int tag = end_tags[s];
        out_path[s*64 + 63] = (float)tag;
        for (int tt = 63; tt >= 1; --tt) {
            tag = lbp[tt*NTAGS + tag];
            out_path[s*64 + tt - 1] = (float)tag;
        }
    }
}

// ---------------------------------------------------------------------------
extern "C" void kernel_launch(void* const* d_in, const int* in_sizes, int n_in,
                              void* d_out, int out_size, void* d_ws, size_t ws_size,
                              hipStream_t stream)
{
    const int*   sent   = (const int*)d_in[0];
    const float* emb    = (const float*)d_in[1];
    const float* w_ih_f = (const float*)d_in[2];
    const float* w_hh_f = (const float*)d_in[3];
    const float* b_ih_f = (const float*)d_in[4];
    const float* b_hh_f = (const float*)d_in[5];
    const float* w_ih_b = (const float*)d_in[6];
    const float* w_hh_b = (const float*)d_in[7];
    const float* b_ih_b = (const float*)d_in[8];
    const float* b_hh_b = (const float*)d_in[9];
    const float* w_tag  = (const float*)d_in[10];
    const float* b_tag  = (const float*)d_in[11];
    const float* trans  = (const float*)d_in[12];
    const float* h0     = (const float*)d_in[13];
    const float* c0     = (const float*)d_in[14];
    float* out = (float*)d_out;

    char* ws = (char*)d_ws;
    size_t off = 0;
    auto alloc = [&](size_t bytes) {
        char* p = ws + off; off += (bytes + 255) & ~(size_t)255; return p;
    };
    float* xg      = (float*)alloc((size_t)2*T_SEQ*G4*sizeof(float));      // 64 MB
    uint32_t* h_hist = (uint32_t*)alloc((size_t)2*T_SEQ*HDIM*sizeof(float)); // 16 MB
    float* feats   = (float*)alloc((size_t)T_SEQ*NTAGS*sizeof(float));
    unsigned char* bp     = (unsigned char*)alloc((size_t)T_SEQ*NTAGS);
    unsigned char* segmap = (unsigned char*)alloc(64*NTAGS);
    int* best_tag = (int*)alloc(sizeof(int));
    int* end_tags = (int*)alloc(64*sizeof(int));
    int* claim    = (int*)alloc(8*sizeof(int));

    if (off > ws_size) {   // diagnostic sentinel: workspace too small
        hipMemsetAsync(d_out, 0xFF, 4, stream);
        return;
    }

    // h_hist = 0xFFFFFFFF sentinel (data-is-the-flag; harness poison is 0xAA)
    hipMemsetAsync(h_hist, 0xFF, (size_t)2*T_SEQ*HDIM*sizeof(float), stream);
    hipMemsetAsync(claim, 0, 8*sizeof(int), stream);

    dim3 gg(G4/64, T_SEQ/64, 2);
    gemm_xg_kernel<<<gg, 256, 0, stream>>>(sent, emb,
        w_ih_f, b_ih_f, b_hh_f, w_ih_b, b_ih_b, b_hh_b, xg);
    bilstm_kernel<<<512, 512, 0, stream>>>(w_hh_f, w_hh_b, h0, c0, xg, h_hist, claim);
    feats_kernel<<<T_SEQ, 256, 0, stream>>>((const float*)h_hist, w_tag, b_tag, feats);
    viterbi_fwd_kernel<<<1, 64, 0, stream>>>(feats, trans, out, bp, best_tag);
    bt_compose_kernel<<<64, 64, 0, stream>>>(bp, segmap);
    bt_final_kernel<<<1, 64, 0, stream>>>(segmap, best_tag, end_tags);
    bt_write_kernel<<<64, 64, 0, stream>>>(bp, end_tags, out + 1);
}

// Round 3
// 8295.603 us; speedup vs baseline: 1.0968x; 1.0968x over previous
//
#include <hip/hip_runtime.h>
#include <cstdint>
#include <cstddef>

#define T_SEQ 4096
#define EMB_D 512
#define HDIM 512
#define G4 2048
#define NTAGS 24
#define START_TAG 22
#define STOP_TAG 23
#define NEGV -10000.0f
#define NBLK 32      // persistent blocks per direction
#define HSLICE 16    // hidden units per block
#define SENT 0xFFFFFFFFu   // -NaN bit pattern; |h|<1 can never equal this

// ---------------------------------------------------------------------------
// 1) xg[dir][t][j] = dot(emb[sent[t]], w_ih[j]) + b_ih[j] + b_hh[j]
// ---------------------------------------------------------------------------
__global__ __launch_bounds__(256) void gemm_xg_kernel(
    const int* __restrict__ sent, const float* __restrict__ emb,
    const float* __restrict__ w_ih_f, const float* __restrict__ b_ih_f, const float* __restrict__ b_hh_f,
    const float* __restrict__ w_ih_b, const float* __restrict__ b_ih_b, const float* __restrict__ b_hh_b,
    float* __restrict__ xg)
{
    const int dir = blockIdx.z;
    const float* W  = dir ? w_ih_b : w_ih_f;
    const float* bi = dir ? b_ih_b : b_ih_f;
    const float* bh = dir ? b_hh_b : b_hh_f;
    const int m0 = blockIdx.y * 64;   // t
    const int n0 = blockIdx.x * 64;   // gate row j
    const int tid = threadIdx.x;

    __shared__ __attribute__((aligned(16))) float As[32][64];  // [k][t]
    __shared__ __attribute__((aligned(16))) float Bs[32][64];  // [k][j]

    const int lrow = tid >> 2;          // 0..63
    const int lk   = (tid & 3) * 8;     // 0,8,16,24

    const int srow = sent[m0 + lrow];
    const float* aptr = emb + (size_t)srow * EMB_D + lk;
    const float* bptr = W   + (size_t)(n0 + lrow) * EMB_D + lk;

    const int ty = tid >> 4;   // 0..15 (M)
    const int tx = tid & 15;   // 0..15 (N)

    float acc[4][4];
    #pragma unroll
    for (int i = 0; i < 4; ++i)
        #pragma unroll
        for (int j = 0; j < 4; ++j) acc[i][j] = 0.f;

    for (int kk = 0; kk < EMB_D; kk += 32) {
        float4 a0 = *(const float4*)(aptr + kk);
        float4 a1 = *(const float4*)(aptr + kk + 4);
        float4 b0 = *(const float4*)(bptr + kk);
        float4 b1 = *(const float4*)(bptr + kk + 4);
        __syncthreads();   // previous iteration's compute done before overwrite
        As[lk+0][lrow]=a0.x; As[lk+1][lrow]=a0.y; As[lk+2][lrow]=a0.z; As[lk+3][lrow]=a0.w;
        As[lk+4][lrow]=a1.x; As[lk+5][lrow]=a1.y; As[lk+6][lrow]=a1.z; As[lk+7][lrow]=a1.w;
        Bs[lk+0][lrow]=b0.x; Bs[lk+1][lrow]=b0.y; Bs[lk+2][lrow]=b0.z; Bs[lk+3][lrow]=b0.w;
        Bs[lk+4][lrow]=b1.x; Bs[lk+5][lrow]=b1.y; Bs[lk+6][lrow]=b1.z; Bs[lk+7][lrow]=b1.w;
        __syncthreads();
        #pragma unroll
        for (int k = 0; k < 32; ++k) {
            float4 av = *(const float4*)&As[k][ty*4];
            float4 bv = *(const float4*)&Bs[k][tx*4];
            acc[0][0]+=av.x*bv.x; acc[0][1]+=av.x*bv.y; acc[0][2]+=av.x*bv.z; acc[0][3]+=av.x*bv.w;
            acc[1][0]+=av.y*bv.x; acc[1][1]+=av.y*bv.y; acc[1][2]+=av.y*bv.z; acc[1][3]+=av.y*bv.w;
            acc[2][0]+=av.z*bv.x; acc[2][1]+=av.z*bv.y; acc[2][2]+=av.z*bv.z; acc[2][3]+=av.z*bv.w;
            acc[3][0]+=av.w*bv.x; acc[3][1]+=av.w*bv.y; acc[3][2]+=av.w*bv.z; acc[3][3]+=av.w*bv.w;
        }
    }
    #pragma unroll
    for (int i = 0; i < 4; ++i) {
        const int t = m0 + ty*4 + i;
        float* crow = xg + ((size_t)dir*T_SEQ + t) * G4 + n0 + tx*4;
        #pragma unroll
        for (int j = 0; j < 4; ++j) {
            const int jg = n0 + tx*4 + j;
            crow[j] = acc[i][j] + bi[jg] + bh[jg];
        }
    }
}

// ---------------------------------------------------------------------------
// 2) Bidirectional LSTM, XCD co-location. ROUND 3: SYMMETRIC ROW-SPLIT.
//    R1/R2 nulls showed the dot-input/scheduling path is not critical; the
//    residual ~2400cy/step is attributed to the asymmetric wave-0 serial tail
//    (part-reduce + transcendentals + shfls + store AFTER the barrier) making
//    wave 0 the straggler at every barrier, compounding with the 32-producer
//    max. This version makes all 8 waves symmetric:
//      wave q owns hidden units {2q, 2q+1} = 8 gate rows; each 8-lane group
//      computes one row; lane i of a group runs the IDENTICAL 64-FMA chain
//      over h-segment i that wave i used to compute part[i] before (bit-exact
//      partials). Partials combined by a LEFT-FOLD shuffle gather
//      (g = xv + P0 + ... + P7 — same order as the old part[] reduction),
//      activations identical, gates gathered by 4 shfls, c/h updated + stored
//      by lanes 0/32. No part[] LDS, no post-barrier tail, no straggler wave.
//    One barrier per step (hbuf publish); hbuf double-buffered and padded
//    (+4 floats per 64-seg) so the segment reads are conflict-free broadcasts.
// ---------------------------------------------------------------------------
__global__ __attribute__((amdgpu_waves_per_eu(2, 2))) __launch_bounds__(512)
void bilstm_kernel(
    const float* __restrict__ w_hh_f, const float* __restrict__ w_hh_b,
    const float* __restrict__ h0, const float* __restrict__ c0,
    const float* __restrict__ xg,
    uint32_t* __restrict__ h_hist,   // [2][T][HDIM] float bits, pre-set SENT
    int* __restrict__ claim)         // [8] per-XCD rank counters, pre-zeroed
{
    uint32_t xcc;
    asm volatile("s_getreg_b32 %0, hwreg(HW_REG_XCC_ID)" : "=s"(xcc));
    xcc &= 7u;

    __shared__ int rank_s;
    if (threadIdx.x == 0)
        rank_s = __hip_atomic_fetch_add(&claim[xcc], 1, __ATOMIC_RELAXED,
                                        __HIP_MEMORY_SCOPE_AGENT);
    __syncthreads();
    const int rank = rank_s;

    int dir;
    if (xcc == 0) dir = 0;
    else if (xcc == 1) dir = 1;
    else return;
    if (rank >= NBLK) return;
    const int b = rank;

    const int tid = threadIdx.x;    // 512
    const int q   = tid >> 6;       // wave 0..7
    const int l   = tid & 63;       // lane
    const int r   = l >> 3;         // row-in-wave 0..7
    const int i   = l & 7;          // segment index 0..7
    const int gate = r & 3;         // 0=i 1=f 2=g 3=o
    const int huo  = r >> 2;        // 0/1 -> hidden unit 2q+huo
    const int row  = gate * HDIM + b * HSLICE + 2*q + huo;   // global gate row

    // weights: lane dots h[64i .. 64i+63] against w_hh[row][64i..64i+63]
    const float* Wrow = (dir ? w_hh_b : w_hh_f) + (size_t)row * HDIM + i * 64;
    float w[64];
    #pragma unroll
    for (int j = 0; j < 16; ++j) {
        float4 v = ((const float4*)Wrow)[j];
        w[4*j+0]=v.x; w[4*j+1]=v.y; w[4*j+2]=v.z; w[4*j+3]=v.w;
    }
    // Pin weights in VGPRs (R5: 7.17->6.63ms; budget 256 via waves_per_eu(2,2))
    #pragma unroll
    for (int ii = 0; ii < 64; ++ii) asm volatile("" : "+v"(w[ii]));

    // padded, double-buffered h staging: segment s at [buf][68*s .. 68*s+63]
    // (68-stride => segment bases hit banks 4s: 8 disjoint 4-bank groups,
    //  conflict-free broadcast ds_read_b128; writes are 2-way = free)
    __shared__ __attribute__((aligned(16))) float hbuf[2][544];

    // c state: lanes 0 and 32 hold c for hidden units 2q and 2q+1
    float c = 0.f;
    if (i == 0 && gate == 0)   // l==0 or l==32
        c = c0[dir*HDIM + b*HSLICE + 2*q + huo];

    const float* xgd = xg + (size_t)dir * T_SEQ * G4;
    uint32_t* hh = h_hist + (size_t)dir * T_SEQ * HDIM;
    const bool leader = (i == 0);

    // preload xg for idx=0 (leader lanes only)
    float xv_cur = 0.f;
    if (leader) {
        const int t0 = dir ? (T_SEQ - 1) : 0;
        xv_cur = xgd[(size_t)t0 * G4 + row];
    }

    for (int idx = 0; idx < T_SEQ; ++idx) {
        const int t = dir ? (T_SEQ - 1 - idx) : idx;
        const int p = idx & 1;

        // -- poll h[t-1][tid] (one value per thread, data-is-the-flag) --
        float hv;
        if (idx == 0) {
            hv = h0[dir*HDIM + tid];
        } else {
            const int tprev = dir ? (t + 1) : (t - 1);
            const uint32_t* wp = hh + (size_t)tprev*HDIM + tid;
            uint32_t u;
            do {
                u = __hip_atomic_load(wp, __ATOMIC_RELAXED, __HIP_MEMORY_SCOPE_AGENT);
            } while (u == SENT);
            union { uint32_t uu; float f; } cv; cv.uu = u;
            hv = cv.f;
        }
        hbuf[p][q*68 + l] = hv;
        __syncthreads();                       // B1: h published in LDS

        // prefetch next step's xg (leaders); consumed after next B1
        float xv_nxt = 0.f;
        if (leader && idx + 1 < T_SEQ) {
            const int tn = dir ? (t - 1) : (t + 1);
            xv_nxt = xgd[(size_t)tn * G4 + row];
        }

        // -- per-lane partial: identical FMA chain to old part[i] --
        const float4* hb4 = (const float4*)&hbuf[p][i*68];
        float s = 0.f;
        #pragma unroll
        for (int j = 0; j < 16; ++j) {
            float4 hvv = hb4[j];               // broadcast across 8 lanes
            s += w[4*j+0]*hvv.x + w[4*j+1]*hvv.y + w[4*j+2]*hvv.z + w[4*j+3]*hvv.w;
        }

        // -- left-fold gather: g = xv + P0 + P1 + ... + P7 (old reduce order)
        const int gbase = l & ~7;              // leader lane of this row group
        float g = xv_cur + s;                  // leader: xv + P0 (s==P0 on leader)
        #pragma unroll
        for (int j = 1; j < 8; ++j) {
            float pj = __shfl(s, gbase + j);
            g += pj;
        }
        // NOTE: on non-leader lanes g is garbage; only leaders' g is consumed.

        // -- activation (leaders), same formulas as before --
        float act = (gate == 2) ? tanhf(g) : 1.f/(1.f + expf(-g));

        // -- gather 4 gates for this wave's 2 hidden units --
        const int base = l & 32;               // 0 for hu 2q, 32 for hu 2q+1
        float iv = __shfl(act, base + 0);
        float fg = __shfl(act, base + 8);
        float gv = __shfl(act, base + 16);
        float ov = __shfl(act, base + 24);

        if ((l & 31) == 0) {                   // lanes 0 and 32
            c = fg*c + iv*gv;
            union { float f; uint32_t u; } hb; hb.f = ov * tanhf(c);
            __hip_atomic_store(hh + (size_t)t*HDIM + b*HSLICE + 2*q + (l>>5), hb.u,
                               __ATOMIC_RELAXED, __HIP_MEMORY_SCOPE_AGENT);
        }
        xv_cur = xv_nxt;
        // hbuf rewrite hazard: next write targets hbuf[p^1]; the earliest
        // rewrite of hbuf[p] is at idx+2, reachable only after B1(idx+1),
        // which every wave joins after finishing its reads of hbuf[p] at idx.
    }
}

// ---------------------------------------------------------------------------
// 3) feats[t][tag] = b_tag[tag] + [hf|hb] . w_tag[tag]
// ---------------------------------------------------------------------------
__global__ __launch_bounds__(256) void feats_kernel(
    const float* __restrict__ h_hist, const float* __restrict__ w_tag,
    const float* __restrict__ b_tag, float* __restrict__ feats)
{
    const int t = blockIdx.x;
    const int tid = threadIdx.x;
    __shared__ __attribute__((aligned(16))) float h[1024];
    __shared__ float partl[192];
    for (int i = tid; i < 512; i += 256) {
        h[i]     = h_hist[(size_t)t*HDIM + i];
        h[512+i] = h_hist[(size_t)T_SEQ*HDIM + (size_t)t*HDIM + i];
    }
    __syncthreads();
    if (tid < 192) {
        const int tag = tid >> 3, p = tid & 7;
        const float* wr = w_tag + (size_t)tag*1024 + p*128;
        const float* hp = h + p*128;
        float s = 0.f;
        #pragma unroll 8
        for (int j = 0; j < 128; ++j) s += wr[j]*hp[j];
        partl[tid] = s;
    }
    __syncthreads();
    if (tid < NTAGS) {
        float s = b_tag[tid];
        #pragma unroll
        for (int p = 0; p < 8; ++p) s += partl[tid*8+p];
        feats[(size_t)t*NTAGS + tid] = s;
    }
}

// ---------------------------------------------------------------------------
// 4) Viterbi forward: single wave, LDS broadcast (R2 version — the R5 shfl
//    rewrite regressed 1.6ms; reverted). Strict > keeps FIRST argmax.
// ---------------------------------------------------------------------------
__global__ void viterbi_fwd_kernel(
    const float* __restrict__ feats, const float* __restrict__ trans,
    float* __restrict__ d_out, unsigned char* __restrict__ bp,
    int* __restrict__ best_tag)
{
    const int lane = threadIdx.x;       // 64 threads = 1 wave
    const bool act = lane < NTAGS;
    float tr[NTAGS];
    #pragma unroll
    for (int p = 0; p < NTAGS; ++p)
        tr[p] = act ? trans[lane*NTAGS + p] : NEGV;

    float fv = (lane == START_TAG) ? 0.f : NEGV;
    __shared__ float fvs[NTAGS];
    __shared__ float term[NTAGS];

    float ftn = act ? feats[lane] : 0.f;   // prefetch t=0
    for (int t = 0; t < T_SEQ; ++t) {
        if (act) fvs[lane] = fv;
        __syncthreads();
        float ft = ftn;
        if (act && t + 1 < T_SEQ) ftn = feats[(size_t)(t+1)*NTAGS + lane];
        float bestv = -3.4e38f;
        int argp = 0;
        #pragma unroll
        for (int p = 0; p < NTAGS; ++p) {
            float sc = tr[p] + fvs[p];
            if (sc > bestv) { bestv = sc; argp = p; }
        }
        __syncthreads();   // reads done before next iteration's write
        fv = bestv + ft;
        if (act) bp[(size_t)t*NTAGS + lane] = (unsigned char)argp;
    }
    if (act) { fv += trans[STOP_TAG*NTAGS + lane]; term[lane] = fv; }
    __syncthreads();
    if (lane == 0) {
        float bv = term[0]; int bi = 0;
        #pragma unroll
        for (int p = 1; p < NTAGS; ++p) if (term[p] > bv) { bv = term[p]; bi = p; }
        d_out[0] = bv;
        *best_tag = bi;
    }
}

// ---------------------------------------------------------------------------
// 5) Hierarchical backtrack
// ---------------------------------------------------------------------------
__global__ void bt_compose_kernel(const unsigned char* __restrict__ bp,
                                  unsigned char* __restrict__ segmap)
{
    const int s = blockIdx.x;
    const int tid = threadIdx.x;   // 64
    __shared__ __attribute__((aligned(16))) unsigned char lbp[64*NTAGS];
    const uint32_t* src = (const uint32_t*)(bp + (size_t)s * 64 * NTAGS);
    uint32_t* dst = (uint32_t*)lbp;
    #pragma unroll
    for (int i = 0; i < 6; ++i) dst[tid + 64*i] = src[tid + 64*i];
    __syncthreads();
    if (tid < NTAGS) {
        int m = tid;
        for (int tt = 63; tt >= 0; --tt) m = lbp[tt*NTAGS + m];
        segmap[s*NTAGS + tid] = (unsigned char)m;
    }
}

__global__ void bt_final_kernel(const unsigned char* __restrict__ segmap,
                                const int* __restrict__ best_tag,
                                int* __restrict__ end_tags)
{
    if (threadIdx.x == 0) {
        int tag = *best_tag;
        end_tags[63] = tag;
        for (int s = 63; s >= 1; --s) {
            tag = segmap[s*NTAGS + tag];
            end_tags[s-1] = tag;
        }
    }
}

__global__ void bt_write_kernel(const unsigned char* __restrict__ bp,
                                const int* __restrict__ end_tags,
                                float* __restrict__ out_path)
{
    const int s = blockIdx.x;
    const int tid = threadIdx.x;   // 64
    __shared__ __attribute__((aligned(16))) unsigned char lbp[64*NTAGS];
    const uint32_t* src = (const uint32_t*)(bp + (size_t)s * 64 * NTAGS);
    uint32_t* dst = (uint32_t*)lbp;
    #pragma unroll
    for (int i = 0; i < 6; ++i) dst[tid + 64*i] = src[tid + 64*i];
    __syncthreads();
    if (tid == 0) {
        int tag = end_tags[s];
        out_path[s*64 + 63] = (float)tag;
        for (int tt = 63; tt >= 1; --tt) {
            tag = lbp[tt*NTAGS + tag];
            out_path[s*64 + tt - 1] = (float)tag;
        }
    }
}

// ---------------------------------------------------------------------------
extern "C" void kernel_launch(void* const* d_in, const int* in_sizes, int n_in,
                              void* d_out, int out_size, void* d_ws, size_t ws_size,
                              hipStream_t stream)
{
    const int*   sent   = (const int*)d_in[0];
    const float* emb    = (const float*)d_in[1];
    const float* w_ih_f = (const float*)d_in[2];
    const float* w_hh_f = (const float*)d_in[3];
    const float* b_ih_f = (const float*)d_in[4];
    const float* b_hh_f = (const float*)d_in[5];
    const float* w_ih_b = (const float*)d_in[6];
    const float* w_hh_b = (const float*)d_in[7];
    const float* b_ih_b = (const float*)d_in[8];
    const float* b_hh_b = (const float*)d_in[9];
    const float* w_tag  = (const float*)d_in[10];
    const float* b_tag  = (const float*)d_in[11];
    const float* trans  = (const float*)d_in[12];
    const float* h0     = (const float*)d_in[13];
    const float* c0     = (const float*)d_in[14];
    float* out = (float*)d_out;

    char* ws = (char*)d_ws;
    size_t off = 0;
    auto alloc = [&](size_t bytes) {
        char* p = ws + off; off += (bytes + 255) & ~(size_t)255; return p;
    };
    float* xg      = (float*)alloc((size_t)2*T_SEQ*G4*sizeof(float));      // 64 MB
    uint32_t* h_hist = (uint32_t*)alloc((size_t)2*T_SEQ*HDIM*sizeof(float)); // 16 MB
    float* feats   = (float*)alloc((size_t)T_SEQ*NTAGS*sizeof(float));
    unsigned char* bp     = (unsigned char*)alloc((size_t)T_SEQ*NTAGS);
    unsigned char* segmap = (unsigned char*)alloc(64*NTAGS);
    int* best_tag = (int*)alloc(sizeof(int));
    int* end_tags = (int*)alloc(64*sizeof(int));
    int* claim    = (int*)alloc(8*sizeof(int));

    if (off > ws_size) {   // diagnostic sentinel: workspace too small
        hipMemsetAsync(d_out, 0xFF, 4, stream);
        return;
    }

    // h_hist = 0xFFFFFFFF sentinel (data-is-the-flag; harness poison is 0xAA)
    hipMemsetAsync(h_hist, 0xFF, (size_t)2*T_SEQ*HDIM*sizeof(float), stream);
    hipMemsetAsync(claim, 0, 8*sizeof(int), stream);

    dim3 gg(G4/64, T_SEQ/64, 2);
    gemm_xg_kernel<<<gg, 256, 0, stream>>>(sent, emb,
        w_ih_f, b_ih_f, b_hh_f, w_ih_b, b_ih_b, b_hh_b, xg);
    bilstm_kernel<<<512, 512, 0, stream>>>(w_hh_f, w_hh_b, h0, c0, xg, h_hist, claim);
    feats_kernel<<<T_SEQ, 256, 0, stream>>>((const float*)h_hist, w_tag, b_tag, feats);
    viterbi_fwd_kernel<<<1, 64, 0, stream>>>(feats, trans, out, bp, best_tag);
    bt_compose_kernel<<<64, 64, 0, stream>>>(bp, segmap);
    bt_final_kernel<<<1, 64, 0, stream>>>(segmap, best_tag, end_tags);
    bt_write_kernel<<<64, 64, 0, stream>>>(bp, end_tags, out + 1);
}